// Round 1
// baseline (164.583 us; speedup 1.0000x reference)
//
#include <hip/hip_runtime.h>
#include <hip/hip_bf16.h>
#include <stdint.h>

#define BROWS 32768
#define LATENT 1024
#define HID 512

typedef float f32x4 __attribute__((ext_vector_type(4)));
typedef __bf16 bf16x8 __attribute__((ext_vector_type(8)));
typedef unsigned short us8 __attribute__((ext_vector_type(8)));

__device__ __forceinline__ void gload16(const void* g, void* l) {
  __builtin_amdgcn_global_load_lds(
      (__attribute__((address_space(1))) void*)g,
      (__attribute__((address_space(3))) void*)l, 16, 0, 0);
}

// hi/lo bf16 split: x ~= hi + lo, residual ~2^-17 * |x|
__device__ __forceinline__ void split_bf16(float x, unsigned short& hi, unsigned short& lo) {
  __bf16 h = (__bf16)x;
  float r = x - (float)h;
  __bf16 l = (__bf16)r;
  hi = __builtin_bit_cast(unsigned short, h);
  lo = __builtin_bit_cast(unsigned short, l);
}

__device__ __forceinline__ f32x4 mfma16(bf16x8 a, bf16x8 b, f32x4 c) {
  return __builtin_amdgcn_mfma_f32_16x16x32_bf16(a, b, c, 0, 0, 0);
}

__device__ __forceinline__ bf16x8 ldfrag(const unsigned short* p) {
  return __builtin_bit_cast(bf16x8, *(const us8*)p);
}

// ---------------- prep: W1 (1024x512 f32) -> W1T hi/lo bf16 [512][1024] ----------------
__global__ __launch_bounds__(256) void k_prep_w1t(const float* __restrict__ W1,
                                                  unsigned short* __restrict__ hi,
                                                  unsigned short* __restrict__ lo) {
  __shared__ float t[64][65];
  const int i = threadIdx.x;
  const int k0 = blockIdx.x * 64;  // over LATENT=1024 (16 blocks)
  const int n0 = blockIdx.y * 64;  // over HID=512    (8 blocks)
#pragma unroll
  for (int s = 0; s < 4; s++) {
    const int r = s * 16 + (i >> 4);
    const int c = (i & 15) * 4;
    float4 v = *(const float4*)&W1[(size_t)(k0 + r) * HID + n0 + c];
    t[r][c] = v.x; t[r][c + 1] = v.y; t[r][c + 2] = v.z; t[r][c + 3] = v.w;
  }
  __syncthreads();
#pragma unroll
  for (int s = 0; s < 4; s++) {
    const int n = s * 16 + (i >> 4);
    const int k = (i & 15) * 4;
    unsigned short h[4], l[4];
#pragma unroll
    for (int j = 0; j < 4; j++) split_bf16(t[k + j][n], h[j], l[j]);
    *(ushort4*)&hi[(size_t)(n0 + n) * LATENT + k0 + k] = make_ushort4(h[0], h[1], h[2], h[3]);
    *(ushort4*)&lo[(size_t)(n0 + n) * LATENT + k0 + k] = make_ushort4(l[0], l[1], l[2], l[3]);
  }
}

// ---------------- prep: W2 (512x92 f32) -> W2T hi/lo bf16 [128][512], rows>=92 zero ----
__global__ __launch_bounds__(256) void k_prep_w2t(const float* __restrict__ W2,
                                                  unsigned short* __restrict__ hi,
                                                  unsigned short* __restrict__ lo) {
  const int idx = blockIdx.x * 256 + threadIdx.x;  // 65536 = 128*512
  const int n = idx >> 9, k = idx & 511;
  const float v = (n < 92) ? W2[(size_t)k * 92 + n] : 0.0f;
  unsigned short h, l;
  split_bf16(v, h, l);
  hi[idx] = h;
  lo[idx] = l;
}

// ---------------- GEMM1: h = silu(z @ W1 + b1), hi/lo split output --------------------
__global__ __launch_bounds__(256, 2) void k_gemm1(
    const float* __restrict__ z, const unsigned short* __restrict__ w1h,
    const unsigned short* __restrict__ w1l, const float* __restrict__ b1,
    unsigned short* __restrict__ hh, unsigned short* __restrict__ hl) {
  __shared__ unsigned short Ah[2][4096], Al[2][4096];  // [128][32] bf16 x2 buf
  __shared__ unsigned short Bh[2][4096], Bl[2][4096];  // [128 n][32 k] bf16 x2 buf

  const int tid = threadIdx.x;
  const int bid = blockIdx.x;
  const int swz = (bid & 7) * 128 + (bid >> 3);  // bijective XCD swizzle (1024 blocks)
  const int m0 = (swz >> 2) * 128;
  const int n0 = (swz & 3) * 128;

  const int w = tid >> 6, lane = tid & 63;
  const int wr = w >> 1, wc = w & 1;
  const int l15 = lane & 15, lg = lane >> 4;

  const int arow = tid >> 3;          // z staging: rows arow + s*32
  const int acol = (tid & 7) << 2;    // 4-float chunks
  const int brow = tid >> 2;          // W1T staging: rows brow + s*64
  const int bc8 = (tid & 3) << 3;

  const float* zb = z + (size_t)(m0 + arow) * LATENT + acol;
  const unsigned short* w1hb = w1h + (size_t)(n0 + brow) * LATENT + bc8;
  const unsigned short* w1lb = w1l + (size_t)(n0 + brow) * LATENT + bc8;

  f32x4 acc[4][4] = {};
  float4 zr[4];

#define G1_STAGE_Z(kt) { \
    const float* p_ = zb + (kt) * 32; \
    zr[0] = *(const float4*)(p_); \
    zr[1] = *(const float4*)(p_ + 32 * LATENT); \
    zr[2] = *(const float4*)(p_ + 64 * LATENT); \
    zr[3] = *(const float4*)(p_ + 96 * LATENT); }

#define G1_STAGE_B(kt, bf) { \
    gload16(w1hb + (kt) * 32,               &Bh[bf][(w << 9)]); \
    gload16(w1hb + (kt) * 32 + 64 * LATENT, &Bh[bf][2048 + (w << 9)]); \
    gload16(w1lb + (kt) * 32,               &Bl[bf][(w << 9)]); \
    gload16(w1lb + (kt) * 32 + 64 * LATENT, &Bl[bf][2048 + (w << 9)]); }

#define G1_WRITE_A(bf) { \
    _Pragma("unroll") \
    for (int s_ = 0; s_ < 4; s_++) { \
      unsigned short h0, h1, h2, h3, l0, l1, l2, l3; \
      split_bf16(zr[s_].x, h0, l0); split_bf16(zr[s_].y, h1, l1); \
      split_bf16(zr[s_].z, h2, l2); split_bf16(zr[s_].w, h3, l3); \
      const int o_ = ((s_ * 32 + arow) << 5) + acol; \
      *(ushort4*)&Ah[bf][o_] = make_ushort4(h0, h1, h2, h3); \
      *(ushort4*)&Al[bf][o_] = make_ushort4(l0, l1, l2, l3); \
    } }

#define G1_COMPUTE(bf) { \
    bf16x8 ah[4], al[4], bh[4], bl[4]; \
    _Pragma("unroll") \
    for (int mf = 0; mf < 4; mf++) { \
      const int o_ = ((wr * 64 + mf * 16 + l15) << 5) + (lg << 3); \
      ah[mf] = ldfrag(&Ah[bf][o_]); \
      al[mf] = ldfrag(&Al[bf][o_]); \
    } \
    _Pragma("unroll") \
    for (int nf = 0; nf < 4; nf++) { \
      const int o_ = ((wc * 64 + nf * 16 + l15) << 5) + (lg << 3); \
      bh[nf] = ldfrag(&Bh[bf][o_]); \
      bl[nf] = ldfrag(&Bl[bf][o_]); \
    } \
    _Pragma("unroll") \
    for (int mf = 0; mf < 4; mf++) { \
      _Pragma("unroll") \
      for (int nf = 0; nf < 4; nf++) { \
        acc[mf][nf] = mfma16(ah[mf], bh[nf], acc[mf][nf]); \
        acc[mf][nf] = mfma16(al[mf], bh[nf], acc[mf][nf]); \
        acc[mf][nf] = mfma16(ah[mf], bl[nf], acc[mf][nf]); \
      } } }

  G1_STAGE_Z(0);
  G1_STAGE_B(0, 0);
  G1_WRITE_A(0);
  __syncthreads();

#pragma unroll 2
  for (int kt = 0; kt < 32; kt++) {
    const int cur = kt & 1, nx = cur ^ 1;
    if (kt < 31) {
      G1_STAGE_Z(kt + 1);
      G1_STAGE_B(kt + 1, nx);
    }
    G1_COMPUTE(cur);
    if (kt < 31) G1_WRITE_A(nx);
    __syncthreads();
  }

  float b1v[4];
#pragma unroll
  for (int nf = 0; nf < 4; nf++) b1v[nf] = b1[n0 + wc * 64 + nf * 16 + l15];

#pragma unroll
  for (int mf = 0; mf < 4; mf++) {
#pragma unroll
    for (int nf = 0; nf < 4; nf++) {
#pragma unroll
      for (int r = 0; r < 4; r++) {
        const int gm = m0 + wr * 64 + mf * 16 + (lg << 2) + r;
        const int gn = n0 + wc * 64 + nf * 16 + l15;
        const float x = acc[mf][nf][r] + b1v[nf];
        const float hval = x / (1.0f + expf(-x));  // silu
        unsigned short hi_, lo_;
        split_bf16(hval, hi_, lo_);
        const size_t o = (size_t)gm * HID + gn;
        hh[o] = hi_;
        hl[o] = lo_;
      }
    }
  }
}

// ---------------- GEMM2 + normalize/softplus/FK epilogue ------------------------------
__global__ __launch_bounds__(256, 2) void k_gemm2(
    const unsigned short* __restrict__ hh, const unsigned short* __restrict__ hl,
    const unsigned short* __restrict__ w2h, const unsigned short* __restrict__ w2l,
    const float* __restrict__ b2, float* __restrict__ out) {
  __shared__ unsigned short Ah[2][2048], Al[2][2048];  // [64][32]
  __shared__ unsigned short Bh[2][4096], Bl[2][4096];  // [128][32]
  __shared__ float raw[64][97];                        // +1 pad: no stride-96 conflicts

  const int tid = threadIdx.x;
  const int m0 = blockIdx.x * 64;
  const int w = tid >> 6, lane = tid & 63;
  const int wr = w >> 1, wc = w & 1;
  const int l15 = lane & 15, lg = lane >> 4;
  const int arow = tid >> 2, ac8 = (tid & 3) << 3;

  const unsigned short* hhb = hh + (size_t)(m0 + arow) * HID + ac8;
  const unsigned short* hlb = hl + (size_t)(m0 + arow) * HID + ac8;
  const unsigned short* w2hb = w2h + (size_t)arow * HID + ac8;
  const unsigned short* w2lb = w2l + (size_t)arow * HID + ac8;

  f32x4 acc[2][3] = {};

#define G2_STAGE(kt, bf) { \
    gload16(hhb + (kt) * 32, &Ah[bf][(w << 9)]); \
    gload16(hlb + (kt) * 32, &Al[bf][(w << 9)]); \
    gload16(w2hb + (kt) * 32,            &Bh[bf][(w << 9)]); \
    gload16(w2hb + (kt) * 32 + 64 * HID, &Bh[bf][2048 + (w << 9)]); \
    gload16(w2lb + (kt) * 32,            &Bl[bf][(w << 9)]); \
    gload16(w2lb + (kt) * 32 + 64 * HID, &Bl[bf][2048 + (w << 9)]); }

#define G2_COMPUTE(bf) { \
    bf16x8 ah[2], al[2], bh[3], bl[3]; \
    _Pragma("unroll") \
    for (int mf = 0; mf < 2; mf++) { \
      const int o_ = ((wr * 32 + mf * 16 + l15) << 5) + (lg << 3); \
      ah[mf] = ldfrag(&Ah[bf][o_]); \
      al[mf] = ldfrag(&Al[bf][o_]); \
    } \
    _Pragma("unroll") \
    for (int nf = 0; nf < 3; nf++) { \
      const int o_ = ((wc * 48 + nf * 16 + l15) << 5) + (lg << 3); \
      bh[nf] = ldfrag(&Bh[bf][o_]); \
      bl[nf] = ldfrag(&Bl[bf][o_]); \
    } \
    _Pragma("unroll") \
    for (int mf = 0; mf < 2; mf++) { \
      _Pragma("unroll") \
      for (int nf = 0; nf < 3; nf++) { \
        acc[mf][nf] = mfma16(ah[mf], bh[nf], acc[mf][nf]); \
        acc[mf][nf] = mfma16(al[mf], bh[nf], acc[mf][nf]); \
        acc[mf][nf] = mfma16(ah[mf], bl[nf], acc[mf][nf]); \
      } } }

  G2_STAGE(0, 0);
  __syncthreads();
#pragma unroll 2
  for (int kt = 0; kt < 16; kt++) {
    const int cur = kt & 1, nx = cur ^ 1;
    if (kt < 15) G2_STAGE(kt + 1, nx);
    G2_COMPUTE(cur);
    __syncthreads();
  }

  // acc -> raw LDS (raw = h @ W2, no bias yet; cols 92..95 are zero via W2T pad)
#pragma unroll
  for (int mf = 0; mf < 2; mf++) {
#pragma unroll
    for (int nf = 0; nf < 3; nf++) {
#pragma unroll
      for (int r = 0; r < 4; r++) {
        const int ml = wr * 32 + mf * 16 + (lg << 2) + r;
        const int nl = wc * 48 + nf * 16 + l15;
        raw[ml][nl] = acc[mf][nf][r];
      }
    }
  }
  __syncthreads();

  const size_t OFFB = (size_t)BROWS * 72;   // offsets section
  const size_t LENB = (size_t)BROWS * 144;  // length section

  // phase 1: per (row, joint) -> direction*length, write offsets+length, off in-place
  for (int task = tid; task < 64 * 24; task += 256) {
    const int row = task / 24;
    const int j = task - row * 24;
    const int gm = m0 + row;
    float* orow = out + OFFB + (size_t)gm * 72;
    if (j == 0) {
      orow[0] = 0.0f; orow[1] = 0.0f; orow[2] = 0.0f;
    } else {
      const int c0 = (j - 1) * 4;
      const float vx = raw[row][c0 + 0] + b2[c0 + 0];
      const float vy = raw[row][c0 + 1] + b2[c0 + 1];
      const float vz = raw[row][c0 + 2] + b2[c0 + 2];
      const float wv = raw[row][c0 + 3] + b2[c0 + 3];
      const float nrm = sqrtf(vx * vx + vy * vy + vz * vz);
      const float inv = 1.0f / fmaxf(nrm, 1e-12f);
      const float len = fmaxf(wv, 0.0f) + log1pf(expf(-fabsf(wv)));  // softplus
      const float sc = inv * len;
      const float ox = vx * sc, oy = vy * sc, oz = vz * sc;
      orow[j * 3 + 0] = ox; orow[j * 3 + 1] = oy; orow[j * 3 + 2] = oz;
      out[LENB + (size_t)gm * 23 + (j - 1)] = len;
      raw[row][c0 + 0] = ox; raw[row][c0 + 1] = oy; raw[row][c0 + 2] = oz;
    }
  }
  __syncthreads();

  // phase 2: forward kinematics, one thread per row, fully static unroll
  if (tid < 64) {
    constexpr int PAR[24] = {-1, 0, 0, 0, 1, 2, 3, 4, 5, 6, 7, 8,
                             9, 9, 9, 12, 13, 14, 16, 17, 18, 19, 20, 21};
    const int gm = m0 + tid;
    float e[72];
    e[0] = 0.0f; e[1] = 0.0f; e[2] = 0.0f;
#pragma unroll
    for (int j = 1; j < 24; j++) {
      const int p = PAR[j];
      const int c0 = (j - 1) * 4;
      e[3 * j + 0] = e[3 * p + 0] + raw[tid][c0 + 0];
      e[3 * j + 1] = e[3 * p + 1] + raw[tid][c0 + 1];
      e[3 * j + 2] = e[3 * p + 2] + raw[tid][c0 + 2];
    }
    float4* jo = (float4*)(out + (size_t)gm * 72);
#pragma unroll
    for (int q = 0; q < 18; q++)
      jo[q] = make_float4(e[4 * q + 0], e[4 * q + 1], e[4 * q + 2], e[4 * q + 3]);
  }
}

extern "C" void kernel_launch(void* const* d_in, const int* in_sizes, int n_in,
                              void* d_out, int out_size, void* d_ws, size_t ws_size,
                              hipStream_t stream) {
  const float* z = (const float*)d_in[0];
  const float* W1 = (const float*)d_in[1];
  const float* b1 = (const float*)d_in[2];
  const float* W2 = (const float*)d_in[3];
  const float* b2 = (const float*)d_in[4];
  float* out = (float*)d_out;

  char* ws = (char*)d_ws;
  unsigned short* w1h = (unsigned short*)(ws);                                  // 1 MB
  unsigned short* w1l = (unsigned short*)(ws + (1 << 20));                      // 1 MB
  unsigned short* w2h = (unsigned short*)(ws + (2 << 20));                      // 128 KB
  unsigned short* w2l = (unsigned short*)(ws + (2 << 20) + 131072);             // 128 KB
  unsigned short* hh = (unsigned short*)(ws + ((size_t)4 << 20));               // 32 MB
  unsigned short* hl = (unsigned short*)(ws + ((size_t)4 << 20) + ((size_t)32 << 20));  // 32 MB

  hipLaunchKernelGGL(k_prep_w1t, dim3(16, 8), dim3(256), 0, stream, W1, w1h, w1l);
  hipLaunchKernelGGL(k_prep_w2t, dim3(256), dim3(256), 0, stream, W2, w2h, w2l);
  hipLaunchKernelGGL(k_gemm1, dim3(1024), dim3(256), 0, stream, z, w1h, w1l, b1, hh, hl);
  hipLaunchKernelGGL(k_gemm2, dim3(512), dim3(256), 0, stream, hh, hl, w2h, w2l, b2, out);
}